// Round 14
// baseline (1037.568 us; speedup 1.0000x reference)
//
#include <hip/hip_runtime.h>
#include <hip/hip_cooperative_groups.h>
#include <math.h>

namespace cg = cooperative_groups;

#define N_NODES 8192
#define N_EDGES 262144
#define DIM 256
#define OUTD 64
#define ELLS 128   // ELL stride; P(deg>128) ~ e^-40 for B(262144, 1/8192)

typedef __bf16 bf16x8 __attribute__((ext_vector_type(8)));
typedef float f32x4 __attribute__((ext_vector_type(4)));
typedef unsigned short u16;
typedef u16 u16x4 __attribute__((ext_vector_type(4)));

__device__ inline float bf2f(u16 v) { return __uint_as_float((unsigned)v << 16); }

// round-to-nearest-even split: x = hi + lo, both bf16
__device__ inline void bsplit(float x, u16& h, u16& l) {
    unsigned u = __float_as_uint(x);
    unsigned hi = (u + 0x7FFFu + ((u >> 16) & 1u)) >> 16;
    float fhi = __uint_as_float(hi << 16);
    float lo = x - fhi;
    unsigned ul = __float_as_uint(lo);
    h = (u16)hi;
    l = (u16)((ul + 0x7FFFu + ((ul >> 16) & 1u)) >> 16);
}

__device__ inline u16 f2bf_rne(float x) {
    unsigned u = __float_as_uint(x);
    return (u16)((u + 0x7FFFu + ((u >> 16) & 1u)) >> 16);
}

// ---------------- fused prep: split x + transpose/split weights + zero cursor ----------------

__global__ __launch_bounds__(256) void prep_kernel(const float* __restrict__ x,
                                                   u16* __restrict__ xhi, u16* __restrict__ xlo,
                                                   const float* __restrict__ mlp_w,
                                                   const float* __restrict__ w1,
                                                   const float* __restrict__ w2,
                                                   const float* __restrict__ wm,
                                                   const float* __restrict__ wl,
                                                   u16* __restrict__ wtm_hi, u16* __restrict__ wtm_lo,
                                                   u16* __restrict__ wt1_hi, u16* __restrict__ wt1_lo,
                                                   u16* __restrict__ wt2_hi, u16* __restrict__ wt2_lo,
                                                   u16* __restrict__ wth_hi, u16* __restrict__ wth_lo,
                                                   int* __restrict__ cursor) {
    const int bid = blockIdx.x;
    const int tid = threadIdx.x;

    if (bid < 2048) {  // ---- split_x ----
        int i = bid * 256 + tid;
        float4 v = *reinterpret_cast<const float4*>(&x[(size_t)i * 4]);
        float xs[4] = {v.x, v.y, v.z, v.w};
        u16x4 h4, l4;
#pragma unroll
        for (int j = 0; j < 4; ++j) { u16 h, l; bsplit(xs[j], h, l); h4[j] = h; l4[j] = l; }
        *reinterpret_cast<u16x4*>(&xhi[(size_t)i * 4]) = h4;
        *reinterpret_cast<u16x4*>(&xlo[(size_t)i * 4]) = l4;
        return;
    }
    if (bid >= 2128) {  // ---- zero cursor ----
        cursor[(bid - 2128) * 256 + tid] = 0;
        return;
    }
    // ---- wsplit ----
    const int idx = bid - 2048;
    const int z = idx >> 4;
    const int by = (idx >> 2) & 3;
    const int bx = idx & 3;
    const float* W; u16 *hi, *lo; int N, rowoff;
    if (z == 0)      { W = mlp_w; hi = wtm_hi; lo = wtm_lo; N = 256; rowoff = 0; }
    else if (z == 1) { W = w1;    hi = wt1_hi; lo = wt1_lo; N = 256; rowoff = 0; }
    else if (z == 2) { W = w2;    hi = wt2_hi; lo = wt2_lo; N = 256; rowoff = 0; }
    else if (z == 3) { W = wm;    hi = wth_hi; lo = wth_lo; N = 64;  rowoff = 0; }
    else             { W = wl;    hi = wth_hi; lo = wth_lo; N = 64;  rowoff = 64; }
    if (bx * 64 >= N) return;

    const int k0 = by * 64, n0 = bx * 64;
    __shared__ float lds[64][68];
#pragma unroll
    for (int it = 0; it < 4; ++it) {
        int slot = tid + it * 256;
        int r = slot >> 4;
        int c4 = (slot & 15) * 4;
        float4 v = *reinterpret_cast<const float4*>(&W[(size_t)(k0 + r) * N + n0 + c4]);
        lds[r][c4] = v.x; lds[r][c4 + 1] = v.y; lds[r][c4 + 2] = v.z; lds[r][c4 + 3] = v.w;
    }
    __syncthreads();
#pragma unroll
    for (int it = 0; it < 4; ++it) {
        int slot = tid + it * 256;
        int n = slot >> 4;
        int k4 = (slot & 15) * 4;
        u16x4 h4, l4;
#pragma unroll
        for (int j = 0; j < 4; ++j) {
            u16 h, l;
            bsplit(lds[k4 + j][n], h, l);
            h4[j] = h; l4[j] = l;
        }
        size_t o = (size_t)(rowoff + n0 + n) * 256 + k0 + k4;
        *reinterpret_cast<u16x4*>(&hi[o]) = h4;
        *reinterpret_cast<u16x4*>(&lo[o]) = l4;
    }
}

// ---------------- phase building blocks (shared by coop and fallback paths) ----------------
// GEMM: 32row x 64col tiles; wave w: rows +(w&1)*16, cols +(w>>1)*32 (NT=2).

template <int NCOLS, int OMODE, int TERMS>
__device__ inline void gemm_block(const u16* __restrict__ Ahi, const u16* __restrict__ Alo,
                                  const u16* __restrict__ Bhi, const u16* __restrict__ Blo,
                                  const float* __restrict__ bias, const int* __restrict__ deg,
                                  u16* __restrict__ Chi, u16* __restrict__ Clo) {
    constexpr int NCT = NCOLS / 64;
    const int bid = blockIdx.x;
    if (bid >= 256 * NCT) return;
    const int tid = threadIdx.x;
    const int lane = tid & 63, w = tid >> 6;
    const int lr = lane & 15, kq = lane >> 4;
    const int rt = bid / NCT, ct = bid % NCT;
    const int row0 = rt * 32 + (w & 1) * 16;
    const int col0 = ct * 64 + (w >> 1) * 32;

    f32x4 acc[2];
    acc[0] = (f32x4){0.f, 0.f, 0.f, 0.f};
    acc[1] = (f32x4){0.f, 0.f, 0.f, 0.f};

#pragma unroll
    for (int kt = 0; kt < 8; ++kt) {
        const int k0 = kt * 32 + kq * 8;
        size_t oa = (size_t)(row0 + lr) * 256 + k0;
        bf16x8 ah = *reinterpret_cast<const bf16x8*>(&Ahi[oa]);
        bf16x8 al;
        if (TERMS == 3) al = *reinterpret_cast<const bf16x8*>(&Alo[oa]);
        bf16x8 bh[2], bl[2];
#pragma unroll
        for (int n = 0; n < 2; ++n) {
            size_t ob = (size_t)(col0 + n * 16 + lr) * 256 + k0;
            bh[n] = *reinterpret_cast<const bf16x8*>(&Bhi[ob]);
            bl[n] = *reinterpret_cast<const bf16x8*>(&Blo[ob]);
        }
#pragma unroll
        for (int n = 0; n < 2; ++n) {
            acc[n] = __builtin_amdgcn_mfma_f32_16x16x32_bf16(ah, bh[n], acc[n], 0, 0, 0);
            acc[n] = __builtin_amdgcn_mfma_f32_16x16x32_bf16(ah, bl[n], acc[n], 0, 0, 0);
            if (TERMS == 3)
                acc[n] = __builtin_amdgcn_mfma_f32_16x16x32_bf16(al, bh[n], acc[n], 0, 0, 0);
        }
    }

    float scl[4];
#pragma unroll
    for (int r = 0; r < 4; ++r) {
        int row = row0 + kq * 4 + r;
        scl[r] = deg ? rsqrtf((float)(deg[row] + 1)) : 1.f;
    }
#pragma unroll
    for (int n = 0; n < 2; ++n) {
        int col = col0 + n * 16 + lr;
        float b = bias ? bias[col] : 0.f;
#pragma unroll
        for (int r = 0; r < 4; ++r) {
            int row = row0 + kq * 4 + r;
            float v = (acc[n][r] + b) * scl[r];
            size_t o = (size_t)row * NCOLS + col;
            if (OMODE == 1) {
                u16 h, l; bsplit(v, h, l);
                Chi[o] = h; Clo[o] = l;
            } else {
                Chi[o] = f2bf_rne(v);
            }
        }
    }
}

__device__ inline void agg_block(const u16* __restrict__ xwb, const int* __restrict__ deg,
                                 const int* __restrict__ ell, const float* __restrict__ bias,
                                 u16* __restrict__ ohi, u16* __restrict__ olo) {
    const int wid = threadIdx.x >> 6;
    const int lane = threadIdx.x & 63;
#pragma unroll
    for (int half = 0; half < 2; ++half) {
        const int d = half * 4096 + blockIdx.x * 4 + wid;
        const int dg = deg[d];
        const int* __restrict__ row = &ell[d * ELLS];

        f32x4 acc = {0.f, 0.f, 0.f, 0.f};
        int i = 0;
        for (; i + 4 <= dg; i += 4) {
            int s0 = row[i], s1 = row[i + 1], s2 = row[i + 2], s3 = row[i + 3];
            u16x4 q0 = *reinterpret_cast<const u16x4*>(&xwb[(size_t)s0 * DIM + lane * 4]);
            u16x4 q1 = *reinterpret_cast<const u16x4*>(&xwb[(size_t)s1 * DIM + lane * 4]);
            u16x4 q2 = *reinterpret_cast<const u16x4*>(&xwb[(size_t)s2 * DIM + lane * 4]);
            u16x4 q3 = *reinterpret_cast<const u16x4*>(&xwb[(size_t)s3 * DIM + lane * 4]);
#pragma unroll
            for (int k = 0; k < 4; ++k)
                acc[k] += (bf2f(q0[k]) + bf2f(q1[k])) + (bf2f(q2[k]) + bf2f(q3[k]));
        }
        for (; i < dg; ++i) {
            int s0 = row[i];
            u16x4 q0 = *reinterpret_cast<const u16x4*>(&xwb[(size_t)s0 * DIM + lane * 4]);
#pragma unroll
            for (int k = 0; k < 4; ++k) acc[k] += bf2f(q0[k]);
        }

        u16x4 sq = *reinterpret_cast<const u16x4*>(&xwb[(size_t)d * DIM + lane * 4]);
        float4 bb = *reinterpret_cast<const float4*>(&bias[lane * 4]);
        float bbk[4] = {bb.x, bb.y, bb.z, bb.w};
        const float dd = rsqrtf((float)(dg + 1));
        u16x4 h4, l4;
#pragma unroll
        for (int k = 0; k < 4; ++k) {
            float v = fmaxf(fmaf(dd, acc[k] + bf2f(sq[k]), bbk[k]), 0.f);
            u16 h, l; bsplit(v, h, l);
            h4[k] = h; l4[k] = l;
        }
        *reinterpret_cast<u16x4*>(&ohi[(size_t)d * DIM + lane * 4]) = h4;
        *reinterpret_cast<u16x4*>(&olo[(size_t)d * DIM + lane * 4]) = l4;
    }
}

__device__ inline void head_block(const u16* __restrict__ xwb, const int* __restrict__ deg,
                                  const int* __restrict__ ell,
                                  const float* __restrict__ b_mean,
                                  const float* __restrict__ b_logstd,
                                  const float* __restrict__ noise,
                                  u16* __restrict__ zhi, u16* __restrict__ zlo) {
    const int wid = threadIdx.x >> 6;
    const int lane = threadIdx.x & 63;
    const int p = lane >> 5;
    const int f4 = lane & 31;
#pragma unroll
    for (int half = 0; half < 2; ++half) {
        const int d = half * 4096 + blockIdx.x * 4 + wid;
        const int dg = deg[d];
        const int* __restrict__ row = &ell[d * ELLS];

        f32x4 acc = {0.f, 0.f, 0.f, 0.f};
        int i = p;
        for (; i + 2 < dg; i += 4) {
            int s0 = row[i], s1 = row[i + 2];
            u16x4 q0 = *reinterpret_cast<const u16x4*>(&xwb[(size_t)s0 * 128 + f4 * 4]);
            u16x4 q1 = *reinterpret_cast<const u16x4*>(&xwb[(size_t)s1 * 128 + f4 * 4]);
#pragma unroll
            for (int k = 0; k < 4; ++k) acc[k] += bf2f(q0[k]) + bf2f(q1[k]);
        }
        if (i < dg) {
            int s0 = row[i];
            u16x4 q0 = *reinterpret_cast<const u16x4*>(&xwb[(size_t)s0 * 128 + f4 * 4]);
#pragma unroll
            for (int k = 0; k < 4; ++k) acc[k] += bf2f(q0[k]);
        }
#pragma unroll
        for (int k = 0; k < 4; ++k) acc[k] += __shfl_xor(acc[k], 32);

        u16x4 sq = *reinterpret_cast<const u16x4*>(&xwb[(size_t)d * 128 + f4 * 4]);
        float4 bb = (f4 < 16) ? *reinterpret_cast<const float4*>(&b_mean[f4 * 4])
                              : *reinterpret_cast<const float4*>(&b_logstd[f4 * 4 - 64]);
        float bbk[4] = {bb.x, bb.y, bb.z, bb.w};
        const float dd = rsqrtf((float)(dg + 1));
        float hm[4];
#pragma unroll
        for (int k = 0; k < 4; ++k)
            hm[k] = fmaxf(fmaf(dd, acc[k] + bf2f(sq[k]), bbk[k]), 0.f);

        float other[4];
#pragma unroll
        for (int k = 0; k < 4; ++k) other[k] = __shfl_xor(hm[k], 16);

        if (p == 0 && f4 < 16) {
            float4 nz = *reinterpret_cast<const float4*>(&noise[(size_t)d * OUTD + f4 * 4]);
            float nk[4] = {nz.x, nz.y, nz.z, nz.w};
            u16x4 h4, l4;
#pragma unroll
            for (int k = 0; k < 4; ++k) {
                float z = fmaf(nk[k], expf(other[k]), hm[k]);
                u16 h, l; bsplit(z, h, l);
                h4[k] = h; l4[k] = l;
            }
            *reinterpret_cast<u16x4*>(&zhi[(size_t)d * OUTD + f4 * 4]) = h4;
            *reinterpret_cast<u16x4*>(&zlo[(size_t)d * OUTD + f4 * 4]) = l4;
        }
    }
}

// ---------------- cooperative mid-pipeline (single kernel, 1024 blocks) ----------------

__global__ __launch_bounds__(256, 4) void mid_kernel(
        const int* __restrict__ src, const int* __restrict__ dst,
        int* __restrict__ cursor, int* __restrict__ ell,
        const u16* __restrict__ xhi, const u16* __restrict__ xlo,
        const u16* __restrict__ wtm_hi, const u16* __restrict__ wtm_lo,
        const u16* __restrict__ wt1_hi, const u16* __restrict__ wt1_lo,
        const u16* __restrict__ wt2_hi, const u16* __restrict__ wt2_lo,
        const u16* __restrict__ wth_hi, const u16* __restrict__ wth_lo,
        const float* __restrict__ mlp_b, const float* __restrict__ b1,
        const float* __restrict__ b2, const float* __restrict__ b_mean,
        const float* __restrict__ b_logstd, const float* __restrict__ noise,
        u16* __restrict__ h0hi, u16* __restrict__ h0lo,
        u16* __restrict__ xwb,
        u16* __restrict__ h1hi, u16* __restrict__ h1lo,
        u16* __restrict__ xwcatb,
        u16* __restrict__ zhi, u16* __restrict__ zlo) {
    cg::grid_group grid = cg::this_grid();

    {
        int e = blockIdx.x * 256 + threadIdx.x;
        int d = dst[e];
        int pp = atomicAdd(&cursor[d], 1);
        ell[d * ELLS + pp] = src[e];
    }
    grid.sync();
    gemm_block<256, 1, 3>(xhi, xlo, wtm_hi, wtm_lo, mlp_b, nullptr, h0hi, h0lo);
    grid.sync();
    gemm_block<256, 2, 2>(h0hi, h0lo, wt1_hi, wt1_lo, nullptr, cursor, xwb, nullptr);
    grid.sync();
    agg_block(xwb, cursor, ell, b1, h1hi, h1lo);
    grid.sync();
    gemm_block<256, 2, 2>(h1hi, h1lo, wt2_hi, wt2_lo, nullptr, cursor, xwb, nullptr);
    grid.sync();
    agg_block(xwb, cursor, ell, b2, h0hi, h0lo);
    grid.sync();
    gemm_block<128, 2, 3>(h0hi, h0lo, wth_hi, wth_lo, nullptr, cursor, xwcatb, nullptr);
    grid.sync();
    head_block(xwcatb, cursor, ell, b_mean, b_logstd, noise, zhi, zlo);
}

// ---------------- fallback discrete-phase kernels ----------------

__global__ __launch_bounds__(256) void phase_fill(const int* __restrict__ src,
                                                  const int* __restrict__ dst,
                                                  int* __restrict__ cursor,
                                                  int* __restrict__ ell) {
    int e = blockIdx.x * 256 + threadIdx.x;
    int d = dst[e];
    int p = atomicAdd(&cursor[d], 1);
    ell[d * ELLS + p] = src[e];
}

template <int NCOLS, int OMODE, int TERMS>
__global__ __launch_bounds__(256) void phase_gemm(const u16* __restrict__ Ahi, const u16* __restrict__ Alo,
                                                  const u16* __restrict__ Bhi, const u16* __restrict__ Blo,
                                                  const float* __restrict__ bias, const int* __restrict__ deg,
                                                  u16* __restrict__ Chi, u16* __restrict__ Clo) {
    gemm_block<NCOLS, OMODE, TERMS>(Ahi, Alo, Bhi, Blo, bias, deg, Chi, Clo);
}

__global__ __launch_bounds__(256) void phase_agg(const u16* __restrict__ xwb, const int* __restrict__ deg,
                                                 const int* __restrict__ ell, const float* __restrict__ bias,
                                                 u16* __restrict__ ohi, u16* __restrict__ olo) {
    agg_block(xwb, deg, ell, bias, ohi, olo);
}

__global__ __launch_bounds__(256) void phase_head(const u16* __restrict__ xwb, const int* __restrict__ deg,
                                                  const int* __restrict__ ell,
                                                  const float* __restrict__ b_mean,
                                                  const float* __restrict__ b_logstd,
                                                  const float* __restrict__ noise,
                                                  u16* __restrict__ zhi, u16* __restrict__ zlo) {
    head_block(xwb, deg, ell, b_mean, b_logstd, noise, zhi, zlo);
}

// ---------------- decoder: out = triu(sigmoid(z z^T), 1), split-bf16 MFMA ----------------

__global__ __launch_bounds__(256) void decode_mfma_kernel(const u16* __restrict__ zhi,
                                                          const u16* __restrict__ zlo,
                                                          float* __restrict__ out) {
    const int bi = blockIdx.y, bj = blockIdx.x;
    const int tid = threadIdx.x;

    if (bj < bi) {
        const f32x4 zero = {0.f, 0.f, 0.f, 0.f};
        size_t base = (size_t)bi * 128 * N_NODES + (size_t)bj * 128;
#pragma unroll 4
        for (int t = 0; t < 16; ++t) {
            int slot = tid + t * 256;
            int r = slot >> 5;
            int c = (slot & 31) * 4;
            __builtin_nontemporal_store(zero, reinterpret_cast<f32x4*>(&out[base + (size_t)r * N_NODES + c]));
        }
        return;
    }

    __shared__ float sh[64][132];

    const int lane = tid & 63;
    const int w = tid >> 6;
    const int lr = lane & 15;
    const int kq = lane >> 4;

    f32x4 acc[2][8];
#pragma unroll
    for (int m = 0; m < 2; ++m)
#pragma unroll
        for (int n = 0; n < 8; ++n) acc[m][n] = (f32x4){0.f, 0.f, 0.f, 0.f};

    bf16x8 ah[2][2], al[2][2];
#pragma unroll
    for (int m = 0; m < 2; ++m)
#pragma unroll
        for (int kt = 0; kt < 2; ++kt) {
            size_t idx = (size_t)(bi * 128 + w * 32 + m * 16 + lr) * OUTD + kt * 32 + kq * 8;
            ah[m][kt] = *reinterpret_cast<const bf16x8*>(&zhi[idx]);
            al[m][kt] = *reinterpret_cast<const bf16x8*>(&zlo[idx]);
        }

#pragma unroll
    for (int n = 0; n < 8; ++n) {
        bf16x8 bh[2], bl[2];
#pragma unroll
        for (int kt = 0; kt < 2; ++kt) {
            size_t idx = (size_t)(bj * 128 + n * 16 + lr) * OUTD + kt * 32 + kq * 8;
            bh[kt] = *reinterpret_cast<const bf16x8*>(&zhi[idx]);
            bl[kt] = *reinterpret_cast<const bf16x8*>(&zlo[idx]);
        }
#pragma unroll
        for (int m = 0; m < 2; ++m)
#pragma unroll
            for (int kt = 0; kt < 2; ++kt) {
                acc[m][n] = __builtin_amdgcn_mfma_f32_16x16x32_bf16(ah[m][kt], bh[kt], acc[m][n], 0, 0, 0);
                acc[m][n] = __builtin_amdgcn_mfma_f32_16x16x32_bf16(ah[m][kt], bl[kt], acc[m][n], 0, 0, 0);
                acc[m][n] = __builtin_amdgcn_mfma_f32_16x16x32_bf16(al[m][kt], bh[kt], acc[m][n], 0, 0, 0);
            }
    }

    const bool diag = (bi == bj);
#pragma unroll
    for (int m = 0; m < 2; ++m) {
        __syncthreads();
#pragma unroll
        for (int n = 0; n < 8; ++n)
#pragma unroll
            for (int r = 0; r < 4; ++r)
                sh[w * 16 + kq * 4 + r][n * 16 + lr] = acc[m][n][r];
        __syncthreads();
#pragma unroll
        for (int it = 0; it < 8; ++it) {
            int slot = tid + it * 256;
            int lrow = slot >> 5;
            int col = (slot & 31) * 4;
            int growt = ((lrow >> 4) << 5) + m * 16 + (lrow & 15);
            int gi = bi * 128 + growt;
            int gj = bj * 128 + col;
            float4 v = *reinterpret_cast<const float4*>(&sh[lrow][col]);
            float vals[4] = {v.x, v.y, v.z, v.w};
#pragma unroll
            for (int j = 0; j < 4; ++j) {
                float e = __expf(-vals[j]);
                float s = __builtin_amdgcn_rcpf(1.f + e);
                if (diag && (gj + j) <= gi) s = 0.f;
                vals[j] = s;
            }
            f32x4 o = {vals[0], vals[1], vals[2], vals[3]};
            __builtin_nontemporal_store(o, reinterpret_cast<f32x4*>(&out[(size_t)gi * N_NODES + gj]));
        }
    }
}

// ---------------- launch ----------------

extern "C" void kernel_launch(void* const* d_in, const int* in_sizes, int n_in,
                              void* d_out, int out_size, void* d_ws, size_t ws_size,
                              hipStream_t stream) {
    const float* x        = (const float*)d_in[0];
    const int*   ei       = (const int*)d_in[1];
    const float* noise    = (const float*)d_in[2];
    const float* mlp_w    = (const float*)d_in[3];
    const float* mlp_b    = (const float*)d_in[4];
    const float* w1       = (const float*)d_in[5];
    const float* b1       = (const float*)d_in[6];
    const float* w2       = (const float*)d_in[7];
    const float* b2       = (const float*)d_in[8];
    const float* w_mean   = (const float*)d_in[9];
    const float* b_mean   = (const float*)d_in[10];
    const float* w_logstd = (const float*)d_in[11];
    const float* b_logstd = (const float*)d_in[12];
    float* outf = (float*)d_out;

    // ---- scratch in d_out (fully overwritten by decode at the end) ----
    const size_t S = (size_t)N_NODES * DIM;            // 2,097,152 floats
    u16* h0hi = (u16*)outf;
    u16* h0lo = h0hi + S;                              // [0, S)
    u16* xwb  = (u16*)(outf + S);                      // [S, 1.5S)
    u16* h1hi = (u16*)(outf + 2 * S);
    u16* h1lo = h1hi + S;                              // [2S, 3S)
    u16* xwcatb = (u16*)(outf + 3 * S);                // [3S, 3.25S)
    int* cursor  = (int*)(outf + 3 * S + S / 4);       // 8192 (doubles as degree)
    int* ell     = cursor + N_NODES;                   // 8192*128 ints (4 MB)
    u16* wt = (u16*)(outf + 4 * S);
    u16* wtm_hi = wt;               u16* wtm_lo = wt + 65536;
    u16* wt1_hi = wt + 131072;      u16* wt1_lo = wt + 196608;
    u16* wt2_hi = wt + 262144;      u16* wt2_lo = wt + 327680;
    u16* wth_hi = wt + 393216;      u16* wth_lo = wt + 425984;
    u16* xhi = (u16*)(outf + 5 * S);
    u16* xlo = xhi + S;                                // [5S, 6S)

    u16* zhi = (u16*)d_ws;
    u16* zlo = zhi + (size_t)N_NODES * OUTD;

    const int* srcI = ei;
    const int* dstI = ei + N_EDGES;

    // 1: fused prep (split x, transpose+split weights, zero cursor)
    prep_kernel<<<2160, 256, 0, stream>>>(x, xhi, xlo, mlp_w, w1, w2, w_mean, w_logstd,
                                          wtm_hi, wtm_lo, wt1_hi, wt1_lo,
                                          wt2_hi, wt2_lo, wth_hi, wth_lo, cursor);

    // 2: cooperative mid-pipeline; on ANY failure fall back to discrete phases.
    {
        void* args[] = {
            (void*)&srcI, (void*)&dstI, (void*)&cursor, (void*)&ell,
            (void*)&xhi, (void*)&xlo,
            (void*)&wtm_hi, (void*)&wtm_lo, (void*)&wt1_hi, (void*)&wt1_lo,
            (void*)&wt2_hi, (void*)&wt2_lo, (void*)&wth_hi, (void*)&wth_lo,
            (void*)&mlp_b, (void*)&b1, (void*)&b2, (void*)&b_mean,
            (void*)&b_logstd, (void*)&noise,
            (void*)&h0hi, (void*)&h0lo, (void*)&xwb,
            (void*)&h1hi, (void*)&h1lo, (void*)&xwcatb,
            (void*)&zhi, (void*)&zlo };
        hipError_t cerr = hipLaunchCooperativeKernel((const void*)mid_kernel, dim3(1024),
                                                     dim3(256), args, 0, stream);
        if (cerr != hipSuccess) {
            (void)hipGetLastError();  // clear sticky error
            phase_fill<<<1024, 256, 0, stream>>>(srcI, dstI, cursor, ell);
            phase_gemm<256, 1, 3><<<1024, 256, 0, stream>>>(xhi, xlo, wtm_hi, wtm_lo,
                                                            mlp_b, nullptr, h0hi, h0lo);
            phase_gemm<256, 2, 2><<<1024, 256, 0, stream>>>(h0hi, h0lo, wt1_hi, wt1_lo,
                                                            nullptr, cursor, xwb, nullptr);
            phase_agg<<<1024, 256, 0, stream>>>(xwb, cursor, ell, b1, h1hi, h1lo);
            phase_gemm<256, 2, 2><<<1024, 256, 0, stream>>>(h1hi, h1lo, wt2_hi, wt2_lo,
                                                            nullptr, cursor, xwb, nullptr);
            phase_agg<<<1024, 256, 0, stream>>>(xwb, cursor, ell, b2, h0hi, h0lo);
            phase_gemm<128, 2, 3><<<512, 256, 0, stream>>>(h0hi, h0lo, wth_hi, wth_lo,
                                                           nullptr, cursor, xwcatb, nullptr);
            phase_head<<<1024, 256, 0, stream>>>(xwcatb, cursor, ell,
                                                 b_mean, b_logstd, noise, zhi, zlo);
        }
    }

    // 3: decode
    dim3 gd(N_NODES / 128, N_NODES / 128);
    decode_mfma_kernel<<<gd, 256, 0, stream>>>(zhi, zlo, outf);
}

// Round 15
// 198.343 us; speedup vs baseline: 5.2312x; 5.2312x over previous
//
#include <hip/hip_runtime.h>
#include <math.h>

#define N_NODES 8192
#define N_EDGES 262144
#define DIM 256
#define OUTD 64
#define ELLS 128   // ELL stride; P(deg>128) ~ e^-40 for B(262144, 1/8192)

typedef __bf16 bf16x8 __attribute__((ext_vector_type(8)));
typedef float f32x4 __attribute__((ext_vector_type(4)));
typedef unsigned short u16;
typedef u16 u16x4 __attribute__((ext_vector_type(4)));

__device__ inline float bf2f(u16 v) { return __uint_as_float((unsigned)v << 16); }

// round-to-nearest-even split: x = hi + lo, both bf16
__device__ inline void bsplit(float x, u16& h, u16& l) {
    unsigned u = __float_as_uint(x);
    unsigned hi = (u + 0x7FFFu + ((u >> 16) & 1u)) >> 16;
    float fhi = __uint_as_float(hi << 16);
    float lo = x - fhi;
    unsigned ul = __float_as_uint(lo);
    h = (u16)hi;
    l = (u16)((ul + 0x7FFFu + ((ul >> 16) & 1u)) >> 16);
}

__device__ inline u16 f2bf_rne(float x) {
    unsigned u = __float_as_uint(x);
    return (u16)((u + 0x7FFFu + ((u >> 16) & 1u)) >> 16);
}

// ---------------- fused prep: split x + transpose/split weights + zero cursor ----------------
// blocks [0,2048): split_x ; [2048,2128): wsplit (80 jobs) ; [2128,2160): zero cursor.

__global__ __launch_bounds__(256) void prep_kernel(const float* __restrict__ x,
                                                   u16* __restrict__ xhi, u16* __restrict__ xlo,
                                                   const float* __restrict__ mlp_w,
                                                   const float* __restrict__ w1,
                                                   const float* __restrict__ w2,
                                                   const float* __restrict__ wm,
                                                   const float* __restrict__ wl,
                                                   u16* __restrict__ wtm_hi, u16* __restrict__ wtm_lo,
                                                   u16* __restrict__ wt1_hi, u16* __restrict__ wt1_lo,
                                                   u16* __restrict__ wt2_hi, u16* __restrict__ wt2_lo,
                                                   u16* __restrict__ wth_hi, u16* __restrict__ wth_lo,
                                                   int* __restrict__ cursor) {
    const int bid = blockIdx.x;
    const int tid = threadIdx.x;

    if (bid < 2048) {  // ---- split_x: one float4 per thread ----
        int i = bid * 256 + tid;
        float4 v = *reinterpret_cast<const float4*>(&x[(size_t)i * 4]);
        float xs[4] = {v.x, v.y, v.z, v.w};
        u16x4 h4, l4;
#pragma unroll
        for (int j = 0; j < 4; ++j) { u16 h, l; bsplit(xs[j], h, l); h4[j] = h; l4[j] = l; }
        *reinterpret_cast<u16x4*>(&xhi[(size_t)i * 4]) = h4;
        *reinterpret_cast<u16x4*>(&xlo[(size_t)i * 4]) = l4;
        return;
    }
    if (bid >= 2128) {  // ---- zero cursor ----
        cursor[(bid - 2128) * 256 + tid] = 0;
        return;
    }
    // ---- wsplit: job idx -> (z, by, bx) ----
    const int idx = bid - 2048;           // 0..79
    const int z = idx >> 4;               // 0..4
    const int by = (idx >> 2) & 3;
    const int bx = idx & 3;
    const float* W; u16 *hi, *lo; int N, rowoff;
    if (z == 0)      { W = mlp_w; hi = wtm_hi; lo = wtm_lo; N = 256; rowoff = 0; }
    else if (z == 1) { W = w1;    hi = wt1_hi; lo = wt1_lo; N = 256; rowoff = 0; }
    else if (z == 2) { W = w2;    hi = wt2_hi; lo = wt2_lo; N = 256; rowoff = 0; }
    else if (z == 3) { W = wm;    hi = wth_hi; lo = wth_lo; N = 64;  rowoff = 0; }
    else             { W = wl;    hi = wth_hi; lo = wth_lo; N = 64;  rowoff = 64; }
    if (bx * 64 >= N) return;

    const int k0 = by * 64, n0 = bx * 64;
    __shared__ float lds[64][68];
#pragma unroll
    for (int it = 0; it < 4; ++it) {
        int slot = tid + it * 256;
        int r = slot >> 4;
        int c4 = (slot & 15) * 4;
        float4 v = *reinterpret_cast<const float4*>(&W[(size_t)(k0 + r) * N + n0 + c4]);
        lds[r][c4] = v.x; lds[r][c4 + 1] = v.y; lds[r][c4 + 2] = v.z; lds[r][c4 + 3] = v.w;
    }
    __syncthreads();
#pragma unroll
    for (int it = 0; it < 4; ++it) {
        int slot = tid + it * 256;
        int n = slot >> 4;
        int k4 = (slot & 15) * 4;
        u16x4 h4, l4;
#pragma unroll
        for (int j = 0; j < 4; ++j) {
            u16 h, l;
            bsplit(lds[k4 + j][n], h, l);
            h4[j] = h; l4[j] = l;
        }
        size_t o = (size_t)(rowoff + n0 + n) * 256 + k0 + k4;
        *reinterpret_cast<u16x4*>(&hi[o]) = h4;
        *reinterpret_cast<u16x4*>(&lo[o]) = l4;
    }
}

// ---------------- single-pass ELL build ----------------

__global__ __launch_bounds__(256) void fill_ell_kernel(const int* __restrict__ src,
                                                       const int* __restrict__ dst,
                                                       int* __restrict__ cursor,
                                                       int* __restrict__ ell) {
    int e = blockIdx.x * 256 + threadIdx.x;
    if (e < N_EDGES) {
        int d = dst[e];
        int p = atomicAdd(&cursor[d], 1);
        ell[d * ELLS + p] = src[e];
    }
}

// ---------------- split-bf16 MFMA GEMM ----------------
// OMODE: 1 = split hi/lo out, 2 = single bf16 table out (prescaled by rsqrt(deg+1)).
// TERMS: 3 = hi*hi + hi*lo + lo*hi ; 2 = hi*hi + hi*lo (enough when C rounds to bf16).

template <int MT, int NT, int OMODE, int TERMS>
__global__ __launch_bounds__(256) void gemm_mfma(const u16* __restrict__ Ahi,
                                                 const u16* __restrict__ Alo,
                                                 const u16* __restrict__ Bhi,
                                                 const u16* __restrict__ Blo,
                                                 const float* __restrict__ bias,
                                                 const int* __restrict__ deg,
                                                 u16* __restrict__ Chi,
                                                 u16* __restrict__ Clo,
                                                 int ldc) {
    const int tid = threadIdx.x;
    const int lane = tid & 63, w = tid >> 6;
    const int lr = lane & 15, kq = lane >> 4;
    const int row0 = (blockIdx.y * 4 + w) * (MT * 16);
    const int col0 = blockIdx.x * (NT * 16);

    f32x4 acc[MT][NT];
#pragma unroll
    for (int m = 0; m < MT; ++m)
#pragma unroll
        for (int n = 0; n < NT; ++n) acc[m][n] = (f32x4){0.f, 0.f, 0.f, 0.f};

#pragma unroll
    for (int kt = 0; kt < 8; ++kt) {
        const int k0 = kt * 32 + kq * 8;
        bf16x8 ah[MT], al[MT];
#pragma unroll
        for (int m = 0; m < MT; ++m) {
            size_t o = (size_t)(row0 + m * 16 + lr) * 256 + k0;
            ah[m] = *reinterpret_cast<const bf16x8*>(&Ahi[o]);
            if (TERMS == 3) al[m] = *reinterpret_cast<const bf16x8*>(&Alo[o]);
        }
        bf16x8 bh[NT], bl[NT];
#pragma unroll
        for (int n = 0; n < NT; ++n) {
            size_t o = (size_t)(col0 + n * 16 + lr) * 256 + k0;
            bh[n] = *reinterpret_cast<const bf16x8*>(&Bhi[o]);
            bl[n] = *reinterpret_cast<const bf16x8*>(&Blo[o]);
        }
#pragma unroll
        for (int m = 0; m < MT; ++m)
#pragma unroll
            for (int n = 0; n < NT; ++n) {
                acc[m][n] = __builtin_amdgcn_mfma_f32_16x16x32_bf16(ah[m], bh[n], acc[m][n], 0, 0, 0);
                acc[m][n] = __builtin_amdgcn_mfma_f32_16x16x32_bf16(ah[m], bl[n], acc[m][n], 0, 0, 0);
                if (TERMS == 3)
                    acc[m][n] = __builtin_amdgcn_mfma_f32_16x16x32_bf16(al[m], bh[n], acc[m][n], 0, 0, 0);
            }
    }

    // C/D layout: col = lr, row = kq*4 + r
#pragma unroll
    for (int m = 0; m < MT; ++m) {
        float scl[4];
#pragma unroll
        for (int r = 0; r < 4; ++r) {
            int row = row0 + m * 16 + kq * 4 + r;
            scl[r] = deg ? rsqrtf((float)(deg[row] + 1)) : 1.f;
        }
#pragma unroll
        for (int n = 0; n < NT; ++n) {
            int col = col0 + n * 16 + lr;
            float b = bias ? bias[col] : 0.f;
#pragma unroll
            for (int r = 0; r < 4; ++r) {
                int row = row0 + m * 16 + kq * 4 + r;
                float v = (acc[m][n][r] + b) * scl[r];
                size_t o = (size_t)row * ldc + col;
                if (OMODE == 1) {
                    u16 h, l; bsplit(v, h, l);
                    Chi[o] = h; Clo[o] = l;
                } else {
                    Chi[o] = f2bf_rne(v);
                }
            }
        }
    }
}

// ---------------- GCN aggregation (256 feats): one dst per WAVE, ELL rows ----------------

__global__ __launch_bounds__(256) void agg256_kernel(const u16* __restrict__ xwb,
                                                     const int* __restrict__ deg,
                                                     const int* __restrict__ ell,
                                                     const float* __restrict__ bias,
                                                     u16* __restrict__ ohi,
                                                     u16* __restrict__ olo) {
    const int wid = threadIdx.x >> 6;
    const int lane = threadIdx.x & 63;
    const int d = blockIdx.x * 4 + wid;
    const int dg = deg[d];
    const int* __restrict__ row = &ell[d * ELLS];

    f32x4 acc = {0.f, 0.f, 0.f, 0.f};
    int i = 0;
    for (; i + 4 <= dg; i += 4) {
        int s0 = row[i], s1 = row[i + 1], s2 = row[i + 2], s3 = row[i + 3];
        u16x4 q0 = *reinterpret_cast<const u16x4*>(&xwb[(size_t)s0 * DIM + lane * 4]);
        u16x4 q1 = *reinterpret_cast<const u16x4*>(&xwb[(size_t)s1 * DIM + lane * 4]);
        u16x4 q2 = *reinterpret_cast<const u16x4*>(&xwb[(size_t)s2 * DIM + lane * 4]);
        u16x4 q3 = *reinterpret_cast<const u16x4*>(&xwb[(size_t)s3 * DIM + lane * 4]);
#pragma unroll
        for (int k = 0; k < 4; ++k)
            acc[k] += (bf2f(q0[k]) + bf2f(q1[k])) + (bf2f(q2[k]) + bf2f(q3[k]));
    }
    for (; i < dg; ++i) {
        int s0 = row[i];
        u16x4 q0 = *reinterpret_cast<const u16x4*>(&xwb[(size_t)s0 * DIM + lane * 4]);
#pragma unroll
        for (int k = 0; k < 4; ++k) acc[k] += bf2f(q0[k]);
    }

    u16x4 sq = *reinterpret_cast<const u16x4*>(&xwb[(size_t)d * DIM + lane * 4]);
    float4 bb = *reinterpret_cast<const float4*>(&bias[lane * 4]);
    float bbk[4] = {bb.x, bb.y, bb.z, bb.w};
    const float dd = rsqrtf((float)(dg + 1));
    u16x4 h4, l4;
#pragma unroll
    for (int k = 0; k < 4; ++k) {
        float v = fmaxf(fmaf(dd, acc[k] + bf2f(sq[k]), bbk[k]), 0.f);
        u16 h, l; bsplit(v, h, l);
        h4[k] = h; l4[k] = l;
    }
    *reinterpret_cast<u16x4*>(&ohi[(size_t)d * DIM + lane * 4]) = h4;
    *reinterpret_cast<u16x4*>(&olo[(size_t)d * DIM + lane * 4]) = l4;
}

// ---------------- fused head agg + reparam: one dst per WAVE, ELL rows ----------------

__global__ __launch_bounds__(256) void head_kernel(const u16* __restrict__ xwb,
                                                   const int* __restrict__ deg,
                                                   const int* __restrict__ ell,
                                                   const float* __restrict__ b_mean,
                                                   const float* __restrict__ b_logstd,
                                                   const float* __restrict__ noise,
                                                   u16* __restrict__ zhi,
                                                   u16* __restrict__ zlo) {
    const int wid = threadIdx.x >> 6;
    const int lane = threadIdx.x & 63;
    const int d = blockIdx.x * 4 + wid;
    const int p = lane >> 5;
    const int f4 = lane & 31;
    const int dg = deg[d];
    const int* __restrict__ row = &ell[d * ELLS];

    f32x4 acc = {0.f, 0.f, 0.f, 0.f};
    int i = p;
    for (; i + 2 < dg; i += 4) {
        int s0 = row[i], s1 = row[i + 2];
        u16x4 q0 = *reinterpret_cast<const u16x4*>(&xwb[(size_t)s0 * 128 + f4 * 4]);
        u16x4 q1 = *reinterpret_cast<const u16x4*>(&xwb[(size_t)s1 * 128 + f4 * 4]);
#pragma unroll
        for (int k = 0; k < 4; ++k) acc[k] += bf2f(q0[k]) + bf2f(q1[k]);
    }
    if (i < dg) {
        int s0 = row[i];
        u16x4 q0 = *reinterpret_cast<const u16x4*>(&xwb[(size_t)s0 * 128 + f4 * 4]);
#pragma unroll
        for (int k = 0; k < 4; ++k) acc[k] += bf2f(q0[k]);
    }
#pragma unroll
    for (int k = 0; k < 4; ++k) acc[k] += __shfl_xor(acc[k], 32);

    u16x4 sq = *reinterpret_cast<const u16x4*>(&xwb[(size_t)d * 128 + f4 * 4]);
    float4 bb = (f4 < 16) ? *reinterpret_cast<const float4*>(&b_mean[f4 * 4])
                          : *reinterpret_cast<const float4*>(&b_logstd[f4 * 4 - 64]);
    float bbk[4] = {bb.x, bb.y, bb.z, bb.w};
    const float dd = rsqrtf((float)(dg + 1));
    float hm[4];
#pragma unroll
    for (int k = 0; k < 4; ++k)
        hm[k] = fmaxf(fmaf(dd, acc[k] + bf2f(sq[k]), bbk[k]), 0.f);

    float other[4];
#pragma unroll
    for (int k = 0; k < 4; ++k) other[k] = __shfl_xor(hm[k], 16);

    if (p == 0 && f4 < 16) {  // lanes 0..15: hm = mean quad, other = logstd quad
        float4 nz = *reinterpret_cast<const float4*>(&noise[(size_t)d * OUTD + f4 * 4]);
        float nk[4] = {nz.x, nz.y, nz.z, nz.w};
        u16x4 h4, l4;
#pragma unroll
        for (int k = 0; k < 4; ++k) {
            float z = fmaf(nk[k], expf(other[k]), hm[k]);
            u16 h, l; bsplit(z, h, l);
            h4[k] = h; l4[k] = l;
        }
        *reinterpret_cast<u16x4*>(&zhi[(size_t)d * OUTD + f4 * 4]) = h4;
        *reinterpret_cast<u16x4*>(&zlo[(size_t)d * OUTD + f4 * 4]) = l4;
    }
}

// ---------------- decoder: out = triu(sigmoid(z z^T), 1), split-bf16 MFMA ----------------

__global__ __launch_bounds__(256) void decode_mfma_kernel(const u16* __restrict__ zhi,
                                                          const u16* __restrict__ zlo,
                                                          float* __restrict__ out) {
    const int bi = blockIdx.y, bj = blockIdx.x;
    const int tid = threadIdx.x;

    if (bj < bi) {
        const f32x4 zero = {0.f, 0.f, 0.f, 0.f};
        size_t base = (size_t)bi * 128 * N_NODES + (size_t)bj * 128;
#pragma unroll 4
        for (int t = 0; t < 16; ++t) {
            int slot = tid + t * 256;
            int r = slot >> 5;
            int c = (slot & 31) * 4;
            __builtin_nontemporal_store(zero, reinterpret_cast<f32x4*>(&out[base + (size_t)r * N_NODES + c]));
        }
        return;
    }

    __shared__ float sh[64][132];

    const int lane = tid & 63;
    const int w = tid >> 6;
    const int lr = lane & 15;
    const int kq = lane >> 4;

    f32x4 acc[2][8];
#pragma unroll
    for (int m = 0; m < 2; ++m)
#pragma unroll
        for (int n = 0; n < 8; ++n) acc[m][n] = (f32x4){0.f, 0.f, 0.f, 0.f};

    bf16x8 ah[2][2], al[2][2];
#pragma unroll
    for (int m = 0; m < 2; ++m)
#pragma unroll
        for (int kt = 0; kt < 2; ++kt) {
            size_t idx = (size_t)(bi * 128 + w * 32 + m * 16 + lr) * OUTD + kt * 32 + kq * 8;
            ah[m][kt] = *reinterpret_cast<const bf16x8*>(&zhi[idx]);
            al[m][kt] = *reinterpret_cast<const bf16x8*>(&zlo[idx]);
        }

#pragma unroll
    for (int n = 0; n < 8; ++n) {
        bf16x8 bh[2], bl[2];
#pragma unroll
        for (int kt = 0; kt < 2; ++kt) {
            size_t idx = (size_t)(bj * 128 + n * 16 + lr) * OUTD + kt * 32 + kq * 8;
            bh[kt] = *reinterpret_cast<const bf16x8*>(&zhi[idx]);
            bl[kt] = *reinterpret_cast<const bf16x8*>(&zlo[idx]);
        }
#pragma unroll
        for (int m = 0; m < 2; ++m)
#pragma unroll
            for (int kt = 0; kt < 2; ++kt) {
                acc[m][n] = __builtin_amdgcn_mfma_f32_16x16x32_bf16(ah[m][kt], bh[kt], acc[m][n], 0, 0, 0);
                acc[m][n] = __builtin_amdgcn_mfma_f32_16x16x32_bf16(ah[m][kt], bl[kt], acc[m][n], 0, 0, 0);
                acc[m][n] = __builtin_amdgcn_mfma_f32_16x16x32_bf16(al[m][kt], bh[kt], acc[m][n], 0, 0, 0);
            }
    }

    const bool diag = (bi == bj);
#pragma unroll
    for (int m = 0; m < 2; ++m) {
        __syncthreads();
#pragma unroll
        for (int n = 0; n < 8; ++n)
#pragma unroll
            for (int r = 0; r < 4; ++r)
                sh[w * 16 + kq * 4 + r][n * 16 + lr] = acc[m][n][r];
        __syncthreads();
#pragma unroll
        for (int it = 0; it < 8; ++it) {
            int slot = tid + it * 256;
            int lrow = slot >> 5;
            int col = (slot & 31) * 4;
            int growt = ((lrow >> 4) << 5) + m * 16 + (lrow & 15);
            int gi = bi * 128 + growt;
            int gj = bj * 128 + col;
            float4 v = *reinterpret_cast<const float4*>(&sh[lrow][col]);
            float vals[4] = {v.x, v.y, v.z, v.w};
#pragma unroll
            for (int j = 0; j < 4; ++j) {
                float e = __expf(-vals[j]);
                float s = __builtin_amdgcn_rcpf(1.f + e);
                if (diag && (gj + j) <= gi) s = 0.f;
                vals[j] = s;
            }
            f32x4 o = {vals[0], vals[1], vals[2], vals[3]};
            __builtin_nontemporal_store(o, reinterpret_cast<f32x4*>(&out[(size_t)gi * N_NODES + gj]));
        }
    }
}

// ---------------- launch ----------------

extern "C" void kernel_launch(void* const* d_in, const int* in_sizes, int n_in,
                              void* d_out, int out_size, void* d_ws, size_t ws_size,
                              hipStream_t stream) {
    const float* x        = (const float*)d_in[0];
    const int*   ei       = (const int*)d_in[1];
    const float* noise    = (const float*)d_in[2];
    const float* mlp_w    = (const float*)d_in[3];
    const float* mlp_b    = (const float*)d_in[4];
    const float* w1       = (const float*)d_in[5];
    const float* b1       = (const float*)d_in[6];
    const float* w2       = (const float*)d_in[7];
    const float* b2       = (const float*)d_in[8];
    const float* w_mean   = (const float*)d_in[9];
    const float* b_mean   = (const float*)d_in[10];
    const float* w_logstd = (const float*)d_in[11];
    const float* b_logstd = (const float*)d_in[12];
    float* outf = (float*)d_out;

    // ---- scratch in d_out (fully overwritten by decode at the end) ----
    const size_t S = (size_t)N_NODES * DIM;            // 2,097,152 floats
    u16* h0hi = (u16*)outf;
    u16* h0lo = h0hi + S;                              // [0, S)
    u16* xwb  = (u16*)(outf + S);                      // [S, 1.5S): bf16 table [8192][256]
    u16* h1hi = (u16*)(outf + 2 * S);
    u16* h1lo = h1hi + S;                              // [2S, 3S)
    u16* h2hi = h0hi;                                  // reuse h0 region
    u16* h2lo = h0lo;
    u16* xwcatb = (u16*)(outf + 3 * S);                // [3S, 3.25S): bf16 table [8192][128]
    int* cursor  = (int*)(outf + 3 * S + S / 4);       // 8192 (doubles as degree)
    int* ell     = cursor + N_NODES;                   // 8192*128 ints (4 MB)
    u16* wt = (u16*)(outf + 4 * S);
    u16* wtm_hi = wt;               u16* wtm_lo = wt + 65536;
    u16* wt1_hi = wt + 131072;      u16* wt1_lo = wt + 196608;
    u16* wt2_hi = wt + 262144;      u16* wt2_lo = wt + 327680;
    u16* wth_hi = wt + 393216;      u16* wth_lo = wt + 425984;
    u16* xhi = (u16*)(outf + 5 * S);
    u16* xlo = xhi + S;                                // [5S, 6S)

    u16* zhi = (u16*)d_ws;
    u16* zlo = zhi + (size_t)N_NODES * OUTD;

    const int* srcI = ei;
    const int* dstI = ei + N_EDGES;

    // 1: fused prep (split x, transpose+split weights, zero cursor)
    prep_kernel<<<2160, 256, 0, stream>>>(x, xhi, xlo, mlp_w, w1, w2, w_mean, w_logstd,
                                          wtm_hi, wtm_lo, wt1_hi, wt1_lo,
                                          wt2_hi, wt2_lo, wth_hi, wth_lo, cursor);
    // 2: single-pass ELL build (cursor -> degree)
    fill_ell_kernel<<<N_EDGES / 256, 256, 0, stream>>>(srcI, dstI, cursor, ell);

    dim3 g256(4, 64);
    // 3: h0 = x @ mlp_w + mlp_b (split out, 3-term)
    gemm_mfma<2, 4, 1, 3><<<g256, 256, 0, stream>>>(xhi, xlo, wtm_hi, wtm_lo, mlp_b, nullptr,
                                                    h0hi, h0lo, DIM);
    // 4: xwb = bf16( rsqrt(deg+1) * (h0 @ w1) )  (2-term: output is bf16 anyway)
    gemm_mfma<2, 4, 2, 2><<<g256, 256, 0, stream>>>(h0hi, h0lo, wt1_hi, wt1_lo, nullptr, cursor,
                                                    xwb, nullptr, DIM);
    // 5: agg layer 1
    agg256_kernel<<<N_NODES / 4, 256, 0, stream>>>(xwb, cursor, ell, b1, h1hi, h1lo);
    // 6: xwb = bf16( rsqrt(deg+1) * (h1 @ w2) )  (2-term)
    gemm_mfma<2, 4, 2, 2><<<g256, 256, 0, stream>>>(h1hi, h1lo, wt2_hi, wt2_lo, nullptr, cursor,
                                                    xwb, nullptr, DIM);
    // 7: agg layer 2
    agg256_kernel<<<N_NODES / 4, 256, 0, stream>>>(xwb, cursor, ell, b2, h2hi, h2lo);
    // 8: xwcatb = bf16( rsqrt(deg+1) * (h2 @ [Wm|Wl]) )  (3-term: logstd feeds exp)
    gemm_mfma<1, 4, 2, 3><<<dim3(2, 128), 256, 0, stream>>>(h2hi, h2lo, wth_hi, wth_lo, nullptr, cursor,
                                                            xwcatb, nullptr, 128);
    // 9: fused head agg + reparam + split
    head_kernel<<<N_NODES / 4, 256, 0, stream>>>(xwcatb, cursor, ell,
                                                 b_mean, b_logstd, noise, zhi, zlo);
    // 10: decode
    dim3 gd(N_NODES / 128, N_NODES / 128);
    decode_mfma_kernel<<<gd, 256, 0, stream>>>(zhi, zlo, outf);
}